// Round 1
// baseline (232.475 us; speedup 1.0000x reference)
//
#include <hip/hip_runtime.h>
#include <hip/hip_bf16.h>

// InfoNCE (n_views=1): loss = mean_i [ LSE_{j!=i}(f_i . f_j / T) - f_i . f_{c_i} / T ],
// c_i = y_i + (y_i >= i), f = row-normalized x.
// Fused as bf16 MFMA NT-GEMM (F F^T, 8192x8192x512) + online row LSE partials.

typedef __bf16 bf16x8 __attribute__((ext_vector_type(8)));
typedef float f32x4 __attribute__((ext_vector_type(4)));

#define AS1 __attribute__((address_space(1)))
#define AS3 __attribute__((address_space(3)))

constexpr int NB = 8192;   // batch
constexpr int ND = 512;    // dim
constexpr float INV_T = 1.0f / 0.07f;

__device__ inline unsigned short f2bf(float f) {
    union { float f; unsigned int u; } v; v.f = f;
    unsigned int u = v.u;
    u = u + 0x7fffu + ((u >> 16) & 1u);   // round-to-nearest-even
    return (unsigned short)(u >> 16);
}
__device__ inline float bf2f(unsigned short s) {
    union { unsigned int u; float f; } v; v.u = ((unsigned int)s) << 16;
    return v.f;
}

// ---------------- Kernel 1: normalize rows, fp32 -> bf16 feats; zero accumulator ----
__global__ __launch_bounds__(256) void norm_kernel(const float* __restrict__ x,
                                                   unsigned short* __restrict__ feats,
                                                   float* __restrict__ accum) {
    if (blockIdx.x == 0 && threadIdx.x == 0) accum[0] = 0.0f;
    const int wave = threadIdx.x >> 6;
    const int lane = threadIdx.x & 63;
    const int row = blockIdx.x * 4 + wave;
    const float4* xr = (const float4*)(x + (size_t)row * ND);
    float4 a = xr[lane];        // cols 4*lane .. +3
    float4 b = xr[64 + lane];   // cols 256+4*lane .. +3
    float ss = a.x*a.x + a.y*a.y + a.z*a.z + a.w*a.w
             + b.x*b.x + b.y*b.y + b.z*b.z + b.w*b.w;
    #pragma unroll
    for (int m = 32; m >= 1; m >>= 1) ss += __shfl_xor(ss, m);
    float norm = sqrtf(ss);
    float scale = 1.0f / fmaxf(norm, 1e-12f);
    ushort4 o1, o2;
    o1.x = f2bf(a.x * scale); o1.y = f2bf(a.y * scale);
    o1.z = f2bf(a.z * scale); o1.w = f2bf(a.w * scale);
    o2.x = f2bf(b.x * scale); o2.y = f2bf(b.y * scale);
    o2.z = f2bf(b.z * scale); o2.w = f2bf(b.w * scale);
    ushort4* fr = (ushort4*)(feats + (size_t)row * ND);
    fr[lane]      = o1;
    fr[64 + lane] = o2;
}

// ---------------- Kernel 2: 128x128 tile of F F^T, K=512, fused row-LSE partials ----
// grid (64 j-tiles, 64 i-tiles), 256 threads = 4 waves (2x2, each wave a 64x64 quadrant)
__global__ __launch_bounds__(256) void sim_lse_kernel(const unsigned short* __restrict__ feats,
                                                      float2* __restrict__ partials) {
    __shared__ unsigned short sA[128 * 64];
    __shared__ unsigned short sB[128 * 64];

    const int tid  = threadIdx.x;
    const int lane = tid & 63;
    const int wave = tid >> 6;
    const int wr   = wave >> 1;     // wave row quadrant (0..1)
    const int wc   = wave & 1;      // wave col quadrant (0..1)
    const int bi   = blockIdx.y;
    const int bj   = blockIdx.x;
    const int rowA0 = bi * 128;
    const int rowB0 = bj * 128;

    f32x4 acc[4][4] = {};

    const int m    = lane & 15;
    const int quad = lane >> 4;

    for (int kt = 0; kt < 8; ++kt) {
        const int k0 = kt * 64;
        // stage A[128][64], B[128][64] via direct global->LDS 16B loads
        #pragma unroll
        for (int r = 0; r < 4; ++r) {
            int c   = r * 256 + tid;        // 16B chunk id; lanes consecutive per wave
            int row = c >> 3;
            int kk  = (c & 7) * 8;
            const unsigned short* ga = feats + (size_t)(rowA0 + row) * ND + k0 + kk;
            const unsigned short* gb = feats + (size_t)(rowB0 + row) * ND + k0 + kk;
            __builtin_amdgcn_global_load_lds((const AS1 void*)ga, (AS3 void*)(sA + c * 8), 16, 0, 0);
            __builtin_amdgcn_global_load_lds((const AS1 void*)gb, (AS3 void*)(sB + c * 8), 16, 0, 0);
        }
        __syncthreads();
        #pragma unroll
        for (int ks = 0; ks < 2; ++ks) {
            const int kk = ks * 32 + quad * 8;
            bf16x8 afrag[4], bfrag[4];
            #pragma unroll
            for (int s = 0; s < 4; ++s) {
                afrag[s] = *(const bf16x8*)(sA + (wr * 64 + s * 16 + m) * 64 + kk);
                bfrag[s] = *(const bf16x8*)(sB + (wc * 64 + s * 16 + m) * 64 + kk);
            }
            #pragma unroll
            for (int si = 0; si < 4; ++si)
                #pragma unroll
                for (int sj = 0; sj < 4; ++sj)
                    acc[si][sj] = __builtin_amdgcn_mfma_f32_16x16x32_bf16(
                        afrag[si], bfrag[sj], acc[si][sj], 0, 0, 0);
        }
        __syncthreads();
    }

    // Epilogue: t = s/T, diagonal -> -inf, per-row (max, sum exp) over this wave's 64 cols.
    // C/D layout (16x16x32): col = lane&15, row = quad*4 + reg.
    #pragma unroll
    for (int si = 0; si < 4; ++si) {
        float t[4][4];
        #pragma unroll
        for (int sj = 0; sj < 4; ++sj) {
            const int gcol = rowB0 + wc * 64 + sj * 16 + m;
            #pragma unroll
            for (int r = 0; r < 4; ++r) {
                const int grow = rowA0 + wr * 64 + si * 16 + quad * 4 + r;
                float v = acc[si][sj][r] * INV_T;
                if (grow == gcol) v = -INFINITY;
                t[sj][r] = v;
            }
        }
        #pragma unroll
        for (int r = 0; r < 4; ++r) {
            float mx = fmaxf(fmaxf(t[0][r], t[1][r]), fmaxf(t[2][r], t[3][r]));
            #pragma unroll
            for (int msk = 1; msk < 16; msk <<= 1) mx = fmaxf(mx, __shfl_xor(mx, msk));
            float s = __expf(t[0][r] - mx) + __expf(t[1][r] - mx)
                    + __expf(t[2][r] - mx) + __expf(t[3][r] - mx);
            #pragma unroll
            for (int msk = 1; msk < 16; msk <<= 1) s += __shfl_xor(s, msk);
            if (m == 0) {
                const int grow = rowA0 + wr * 64 + si * 16 + quad * 4 + r;
                partials[(size_t)grow * 128 + bj * 2 + wc] = make_float2(mx, s);
            }
        }
    }
}

// ---------------- Kernel 3: combine 128 partials/row -> LSE; target dot; mean ------
__global__ __launch_bounds__(256) void combine_kernel(const float2* __restrict__ partials,
                                                      const unsigned short* __restrict__ feats,
                                                      const int* __restrict__ y,
                                                      float* __restrict__ accum) {
    __shared__ float red[4];
    const int wave = threadIdx.x >> 6;
    const int lane = threadIdx.x & 63;
    const int row  = blockIdx.x * 4 + wave;

    float2 p1 = partials[(size_t)row * 128 + lane];
    float2 p2 = partials[(size_t)row * 128 + 64 + lane];
    float M = fmaxf(p1.x, p2.x);
    #pragma unroll
    for (int msk = 1; msk < 64; msk <<= 1) M = fmaxf(M, __shfl_xor(M, msk));
    float L = p1.y * __expf(p1.x - M) + p2.y * __expf(p2.x - M);
    #pragma unroll
    for (int msk = 1; msk < 64; msk <<= 1) L += __shfl_xor(L, msk);
    float lse = M + __logf(L);

    // target column c = y + (y >= row); dot(f_row, f_c) in bf16->fp32
    const int yv = y[row];
    const int c  = yv + (yv >= row ? 1 : 0);
    uint4 av = ((const uint4*)(feats + (size_t)row * ND))[lane];
    uint4 bv = ((const uint4*)(feats + (size_t)c   * ND))[lane];
    float dot = 0.0f;
    const unsigned int* au = (const unsigned int*)&av;
    const unsigned int* bu = (const unsigned int*)&bv;
    #pragma unroll
    for (int k = 0; k < 4; ++k) {
        dot += bf2f((unsigned short)(au[k] & 0xffffu)) * bf2f((unsigned short)(bu[k] & 0xffffu));
        dot += bf2f((unsigned short)(au[k] >> 16))     * bf2f((unsigned short)(bu[k] >> 16));
    }
    #pragma unroll
    for (int msk = 1; msk < 64; msk <<= 1) dot += __shfl_xor(dot, msk);

    float loss = lse - dot * INV_T;
    if (lane == 0) red[wave] = loss;
    __syncthreads();
    if (threadIdx.x == 0) {
        float s = red[0] + red[1] + red[2] + red[3];
        atomicAdd(accum, s * (1.0f / (float)NB));
    }
}

// ---------------- Kernel 4: pack result (valid read as fp32 OR bf16) ---------------
__global__ void pack_out(const float* __restrict__ accum, unsigned int* __restrict__ out) {
    float v = accum[0];
    unsigned int b = f2bf(v);
    out[0] = (b << 16) | b;   // fp32 read ~= v (within 2^-8 rel); bf16 read of low half == bf16(v)
}

extern "C" void kernel_launch(void* const* d_in, const int* in_sizes, int n_in,
                              void* d_out, int out_size, void* d_ws, size_t ws_size,
                              hipStream_t stream) {
    const float* x = (const float*)d_in[0];
    const int*   y = (const int*)d_in[1];

    // workspace: [0,8MB) bf16 feats; [8MB,16MB) float2 partials (8192x128); [16MB] accum
    unsigned short* feats    = (unsigned short*)d_ws;
    float2*         partials = (float2*)((char*)d_ws + (size_t)8 * 1024 * 1024);
    float*          accum    = (float*)((char*)d_ws + (size_t)16 * 1024 * 1024);

    norm_kernel<<<NB / 4, 256, 0, stream>>>(x, feats, accum);
    dim3 grid(NB / 128, NB / 128);
    sim_lse_kernel<<<grid, 256, 0, stream>>>(feats, partials);
    combine_kernel<<<NB / 4, 256, 0, stream>>>(partials, feats, y, accum);
    pack_out<<<1, 1, 0, stream>>>(accum, (unsigned int*)d_out);
}

// Round 2
// 180.281 us; speedup vs baseline: 1.2895x; 1.2895x over previous
//
#include <hip/hip_runtime.h>
#include <hip/hip_bf16.h>

// InfoNCE (n_views=1): loss = mean_i [ LSE_{j!=i}(f_i . f_j / T) - f_i . f_{c_i} / T ],
// c_i = y_i + (y_i >= i), f = row-normalized x.
// bf16 MFMA NT-GEMM (F F^T) computed on the UPPER TRIANGLE of 128x128 tiles only
// (sim is symmetric): each off-diagonal tile emits row-wise AND column-wise
// (max, sumexp) partials. LDS uses an XOR swizzle (k8 ^= row&7) to kill the
// 16-way ds_read_b128 bank conflicts of the 128B-stride layout.

typedef __bf16 bf16x8 __attribute__((ext_vector_type(8)));
typedef float f32x4 __attribute__((ext_vector_type(4)));

#define AS1 __attribute__((address_space(1)))
#define AS3 __attribute__((address_space(3)))

constexpr int NB = 8192;   // batch
constexpr int ND = 512;    // dim
constexpr float INV_T = 1.0f / 0.07f;

__device__ inline unsigned short f2bf(float f) {
    union { float f; unsigned int u; } v; v.f = f;
    unsigned int u = v.u;
    u = u + 0x7fffu + ((u >> 16) & 1u);   // round-to-nearest-even
    return (unsigned short)(u >> 16);
}
__device__ inline float bf2f(unsigned short s) {
    union { unsigned int u; float f; } v; v.u = ((unsigned int)s) << 16;
    return v.f;
}

// ---------------- Kernel 1: normalize rows, fp32 -> bf16 feats; zero accumulator ----
__global__ __launch_bounds__(256) void norm_kernel(const float* __restrict__ x,
                                                   unsigned short* __restrict__ feats,
                                                   float* __restrict__ accum) {
    if (blockIdx.x == 0 && threadIdx.x == 0) accum[0] = 0.0f;
    const int wave = threadIdx.x >> 6;
    const int lane = threadIdx.x & 63;
    const int row = blockIdx.x * 4 + wave;
    const float4* xr = (const float4*)(x + (size_t)row * ND);
    float4 a = xr[lane];        // cols 4*lane .. +3
    float4 b = xr[64 + lane];   // cols 256+4*lane .. +3
    float ss = a.x*a.x + a.y*a.y + a.z*a.z + a.w*a.w
             + b.x*b.x + b.y*b.y + b.z*b.z + b.w*b.w;
    #pragma unroll
    for (int m = 32; m >= 1; m >>= 1) ss += __shfl_xor(ss, m);
    float norm = sqrtf(ss);
    float scale = 1.0f / fmaxf(norm, 1e-12f);
    ushort4 o1, o2;
    o1.x = f2bf(a.x * scale); o1.y = f2bf(a.y * scale);
    o1.z = f2bf(a.z * scale); o1.w = f2bf(a.w * scale);
    o2.x = f2bf(b.x * scale); o2.y = f2bf(b.y * scale);
    o2.z = f2bf(b.z * scale); o2.w = f2bf(b.w * scale);
    ushort4* fr = (ushort4*)(feats + (size_t)row * ND);
    fr[lane]      = o1;
    fr[64 + lane] = o2;
}

// ---------------- Kernel 2: upper-tri 128x128 tiles of F F^T, fused LSE partials ----
// 1D grid of 2080 blocks -> (bi, bj) with bi <= bj. 256 threads = 4 waves (2x2
// quadrants of 64x64). LDS rows are 64 bf16 (128 B); chunk k8 is XOR-swizzled
// by (row & 7) so ds_read_b128 lanes spread over all 8 bank groups.
__global__ __launch_bounds__(256) void sim_lse_kernel(const unsigned short* __restrict__ feats,
                                                      float2* __restrict__ partials) {
    __shared__ unsigned short sA[128 * 64];
    __shared__ unsigned short sB[128 * 64];

    const int tid  = threadIdx.x;
    const int lane = tid & 63;
    const int wave = tid >> 6;
    const int wr   = wave >> 1;     // wave row quadrant (0..1)
    const int wc   = wave & 1;      // wave col quadrant (0..1)

    // decode upper-triangle pair: t -> (bi <= bj)
    int t = blockIdx.x;
    int bj = (int)((sqrtf(8.0f * (float)t + 1.0f) - 1.0f) * 0.5f);
    while ((bj + 1) * (bj + 2) / 2 <= t) ++bj;
    while (bj * (bj + 1) / 2 > t) --bj;
    const int bi = t - bj * (bj + 1) / 2;

    const int rowA0 = bi * 128;
    const int rowB0 = bj * 128;

    f32x4 acc[4][4] = {};

    const int m    = lane & 15;
    const int quad = lane >> 4;
    const int sw   = m & 7;         // ds_read swizzle term (row & 7 == m & 7)

    for (int kt = 0; kt < 8; ++kt) {
        const int k0 = kt * 64;
        // stage A[128][64], B[128][64]; LDS slot c holds global chunk k8g = (c&7) ^ (row&7)
        #pragma unroll
        for (int r = 0; r < 4; ++r) {
            int c   = r * 256 + tid;        // 16B chunk id; lanes consecutive per wave
            int row = c >> 3;
            int k8g = (c & 7) ^ (row & 7);
            const unsigned short* ga = feats + (size_t)(rowA0 + row) * ND + k0 + k8g * 8;
            const unsigned short* gb = feats + (size_t)(rowB0 + row) * ND + k0 + k8g * 8;
            __builtin_amdgcn_global_load_lds((const AS1 void*)ga, (AS3 void*)(sA + c * 8), 16, 0, 0);
            __builtin_amdgcn_global_load_lds((const AS1 void*)gb, (AS3 void*)(sB + c * 8), 16, 0, 0);
        }
        __syncthreads();
        #pragma unroll
        for (int ks = 0; ks < 2; ++ks) {
            const int k8 = ks * 4 + quad;   // logical 16B chunk within the row
            bf16x8 afrag[4], bfrag[4];
            #pragma unroll
            for (int s = 0; s < 4; ++s) {
                afrag[s] = *(const bf16x8*)(sA + (wr * 64 + s * 16 + m) * 64 + ((k8 ^ sw) << 3));
                bfrag[s] = *(const bf16x8*)(sB + (wc * 64 + s * 16 + m) * 64 + ((k8 ^ sw) << 3));
            }
            #pragma unroll
            for (int si = 0; si < 4; ++si)
                #pragma unroll
                for (int sj = 0; sj < 4; ++sj)
                    acc[si][sj] = __builtin_amdgcn_mfma_f32_16x16x32_bf16(
                        afrag[si], bfrag[sj], acc[si][sj], 0, 0, 0);
        }
        __syncthreads();
    }

    // ---- Row pass: per-row (max, sumexp) over this wave's 64 cols ----
    // C/D layout (16x16x32): col = lane&15, row = quad*4 + reg.
    #pragma unroll
    for (int si = 0; si < 4; ++si) {
        float tv[4][4];
        #pragma unroll
        for (int sj = 0; sj < 4; ++sj) {
            const int gcol = rowB0 + wc * 64 + sj * 16 + m;
            #pragma unroll
            for (int r = 0; r < 4; ++r) {
                const int grow = rowA0 + wr * 64 + si * 16 + quad * 4 + r;
                float v = acc[si][sj][r] * INV_T;
                if (grow == gcol) v = -INFINITY;   // only hits on diagonal tiles
                tv[sj][r] = v;
            }
        }
        #pragma unroll
        for (int r = 0; r < 4; ++r) {
            float mx = fmaxf(fmaxf(tv[0][r], tv[1][r]), fmaxf(tv[2][r], tv[3][r]));
            #pragma unroll
            for (int msk = 1; msk < 16; msk <<= 1) mx = fmaxf(mx, __shfl_xor(mx, msk));
            float s = __expf(tv[0][r] - mx) + __expf(tv[1][r] - mx)
                    + __expf(tv[2][r] - mx) + __expf(tv[3][r] - mx);
            #pragma unroll
            for (int msk = 1; msk < 16; msk <<= 1) s += __shfl_xor(s, msk);
            if (m == 0) {
                const int grow = rowA0 + wr * 64 + si * 16 + quad * 4 + r;
                partials[(size_t)grow * 128 + bj * 2 + wc] = make_float2(mx, s);
            }
        }
    }

    // ---- Col pass (off-diagonal tiles only): sim[j][i] = sim[i][j] ----
    // Per column gcol, reduce over the wave's 64 rows: 16 regs locally + xor 16/32.
    if (bi != bj) {
        #pragma unroll
        for (int sj = 0; sj < 4; ++sj) {
            float tv[16];
            float mx = -INFINITY;
            #pragma unroll
            for (int si = 0; si < 4; ++si)
                #pragma unroll
                for (int r = 0; r < 4; ++r) {
                    float v = acc[si][sj][r] * INV_T;
                    tv[si * 4 + r] = v;
                    mx = fmaxf(mx, v);
                }
            mx = fmaxf(mx, __shfl_xor(mx, 16));
            mx = fmaxf(mx, __shfl_xor(mx, 32));
            float s = 0.0f;
            #pragma unroll
            for (int k = 0; k < 16; ++k) s += __expf(tv[k] - mx);
            s += __shfl_xor(s, 16);
            s += __shfl_xor(s, 32);
            if (quad == 0) {
                const int gcol = rowB0 + wc * 64 + sj * 16 + m;
                partials[(size_t)gcol * 128 + bi * 2 + wr] = make_float2(mx, s);
            }
        }
    }
}

// ---------------- Kernel 3: combine 128 partials/row -> LSE; target dot; mean ------
__global__ __launch_bounds__(256) void combine_kernel(const float2* __restrict__ partials,
                                                      const unsigned short* __restrict__ feats,
                                                      const int* __restrict__ y,
                                                      float* __restrict__ accum) {
    __shared__ float red[4];
    const int wave = threadIdx.x >> 6;
    const int lane = threadIdx.x & 63;
    const int row  = blockIdx.x * 4 + wave;

    float2 p1 = partials[(size_t)row * 128 + lane];
    float2 p2 = partials[(size_t)row * 128 + 64 + lane];
    float M = fmaxf(p1.x, p2.x);
    #pragma unroll
    for (int msk = 1; msk < 64; msk <<= 1) M = fmaxf(M, __shfl_xor(M, msk));
    float L = p1.y * __expf(p1.x - M) + p2.y * __expf(p2.x - M);
    #pragma unroll
    for (int msk = 1; msk < 64; msk <<= 1) L += __shfl_xor(L, msk);
    float lse = M + __logf(L);

    // target column c = y + (y >= row); dot(f_row, f_c) in bf16->fp32
    const int yv = y[row];
    const int c  = yv + (yv >= row ? 1 : 0);
    uint4 av = ((const uint4*)(feats + (size_t)row * ND))[lane];
    uint4 bv = ((const uint4*)(feats + (size_t)c   * ND))[lane];
    float dot = 0.0f;
    const unsigned int* au = (const unsigned int*)&av;
    const unsigned int* bu = (const unsigned int*)&bv;
    #pragma unroll
    for (int k = 0; k < 4; ++k) {
        dot += bf2f((unsigned short)(au[k] & 0xffffu)) * bf2f((unsigned short)(bu[k] & 0xffffu));
        dot += bf2f((unsigned short)(au[k] >> 16))     * bf2f((unsigned short)(bu[k] >> 16));
    }
    #pragma unroll
    for (int msk = 1; msk < 64; msk <<= 1) dot += __shfl_xor(dot, msk);

    float loss = lse - dot * INV_T;
    if (lane == 0) red[wave] = loss;
    __syncthreads();
    if (threadIdx.x == 0) {
        float s = red[0] + red[1] + red[2] + red[3];
        atomicAdd(accum, s * (1.0f / (float)NB));
    }
}

// ---------------- Kernel 4: pack result (valid read as fp32 OR bf16) ---------------
__global__ void pack_out(const float* __restrict__ accum, unsigned int* __restrict__ out) {
    float v = accum[0];
    unsigned int b = f2bf(v);
    out[0] = (b << 16) | b;   // fp32 read ~= v (within 2^-8 rel); bf16 read of low half == bf16(v)
}

extern "C" void kernel_launch(void* const* d_in, const int* in_sizes, int n_in,
                              void* d_out, int out_size, void* d_ws, size_t ws_size,
                              hipStream_t stream) {
    const float* x = (const float*)d_in[0];
    const int*   y = (const int*)d_in[1];

    // workspace: [0,8MB) bf16 feats; [8MB,16MB) float2 partials (8192x128); [16MB] accum
    unsigned short* feats    = (unsigned short*)d_ws;
    float2*         partials = (float2*)((char*)d_ws + (size_t)8 * 1024 * 1024);
    float*          accum    = (float*)((char*)d_ws + (size_t)16 * 1024 * 1024);

    norm_kernel<<<NB / 4, 256, 0, stream>>>(x, feats, accum);
    const int ntiles = (NB / 128) * (NB / 128 + 1) / 2;   // 2080 upper-tri tiles
    sim_lse_kernel<<<ntiles, 256, 0, stream>>>(feats, partials);
    combine_kernel<<<NB / 4, 256, 0, stream>>>(partials, feats, y, accum);
    pack_out<<<1, 1, 0, stream>>>(accum, (unsigned int*)d_out);
}